// Round 2
// baseline (2687.902 us; speedup 1.0000x reference)
//
#include <hip/hip_runtime.h>
#include <math.h>

#pragma clang fp contract(off)

#define NROWS 131072
#define INDIM 64
#define EMBD  64
#define KCODE 1024
#define DENSE 256

// selu matching np: scale * where(x>0, x, alpha*expm1(x)), each op rounded separately
__device__ __forceinline__ float selu_f(float v) {
    float em  = expm1f(v);
    float neg = 1.6732632423543772f * em;
    float r   = v > 0.0f ? v : neg;
    return 1.0507009873554805f * r;
}

__device__ __forceinline__ float4 ldf4(const float* p) { return *(const float4*)p; }

// ---------- prep 1: transposes W2 [256,256] -> W2T [j][c], W3 [64,256] -> W3T [c][e] ----------
__global__ void prep_transpose(const float* __restrict__ W2, const float* __restrict__ W3,
                               float* __restrict__ W2T, float* __restrict__ W3T) {
    int id = blockIdx.x * 256 + threadIdx.x;
    if (id < 65536) {
        int c = id >> 8, j = id & 255;
        W2T[j * 256 + c] = W2[id];
    }
    int id2 = id - 65536;
    if (id2 >= 0 && id2 < 16384) {
        int e = id2 >> 8, c = id2 & 255;
        W3T[c * 64 + e] = W3[id2];
    }
}

// ---------- prep 2: decoder table dec_out[k] = decoder(emb[k]), and en[k] = ||emb_k||^2 ----------
__global__ void prep_decoder(const float* __restrict__ emb,
                             const float* __restrict__ Wd1, const float* __restrict__ bd1,
                             const float* __restrict__ Wd2, const float* __restrict__ bd2,
                             const float* __restrict__ Wd3, const float* __restrict__ bd3,
                             float* __restrict__ dec_out, float* __restrict__ en) {
    __shared__ float e[64];
    __shared__ float h1[256];
    __shared__ float h2[256];
    const int t = threadIdx.x; // 256 threads
    for (int kc = 0; kc < 4; ++kc) {
        const int k = blockIdx.x * 4 + kc;
        __syncthreads(); // protect smem reuse across iterations
        if (t < 64) e[t] = emb[k * 64 + t];
        __syncthreads();
        {
            float acc = 0.0f;
            const float* w = Wd1 + t * 64;
            #pragma unroll
            for (int j = 0; j < 64; ++j) acc = __builtin_fmaf(w[j], e[j], acc);
            h1[t] = selu_f(acc + bd1[t]);
        }
        __syncthreads();
        {
            float acc = 0.0f;
            const float* w = Wd2 + t * 256;
            #pragma unroll 8
            for (int j = 0; j < 256; ++j) acc = __builtin_fmaf(w[j], h1[j], acc);
            h2[t] = selu_f(acc + bd2[t]);
        }
        __syncthreads();
        if (t < 64) {
            float acc = 0.0f;
            const float* w = Wd3 + t * 256;
            #pragma unroll 8
            for (int j = 0; j < 256; ++j) acc = __builtin_fmaf(w[j], h2[j], acc);
            dec_out[k * 64 + t] = acc + bd3[t];
        }
        if (t == 0) {
            // numpy pairwise sum (n=64 base case): 8 strided accumulators, then balanced tree
            float r[8];
            #pragma unroll
            for (int u = 0; u < 8; ++u) r[u] = e[u] * e[u];
            #pragma unroll
            for (int i = 8; i < 64; i += 8) {
                #pragma unroll
                for (int u = 0; u < 8; ++u) { float p = e[i + u] * e[i + u]; r[u] = r[u] + p; }
            }
            en[k] = ((r[0] + r[1]) + (r[2] + r[3])) + ((r[4] + r[5]) + (r[6] + r[7]));
        }
    }
}

// ---------- main: encoder (fp32, VMEM double-buffered weights) + argmin + gather ----------
// block = 256 threads = 4 waves, 64 rows/block (lane = row), wave w owns col-slice [64w,64w+64)
// All wave-uniform weight loads are laundered through an opaque-zero VGPR so they compile to
// global_load (vmcnt, ordered, pipelinable) instead of s_load (lgkmcnt(0) serialization).
__launch_bounds__(256, 2)
__global__ void vqvae_main(const float* __restrict__ x,
                           const float* __restrict__ W1, const float* __restrict__ b1,
                           const float* __restrict__ b2, const float* __restrict__ b3,
                           const float* __restrict__ W2T, const float* __restrict__ W3T,
                           const float* __restrict__ emb, const float* __restrict__ en,
                           const float* __restrict__ dec_out, float* __restrict__ out) {
    __shared__ float smem[16640];       // phase-aliased: x-stage [64][65] -> h1T [256][65] -> zpart [4][64][65]
    __shared__ float cand_s[4][64];
    __shared__ int   cand_k[4][64];
    __shared__ int   ix[64];

    const int t    = threadIdx.x;
    const int wave = t >> 6;
    const int lane = t & 63;            // row within tile
    const int rowbase = blockIdx.x * 64;

    // opaque zero in a VGPR: defeats uniformity analysis -> keeps loads on the vector pipe
    int lz;
    asm volatile("v_mov_b32 %0, 0" : "=v"(lz));

    // ---- phase 0: stage x tile coalesced, extract own row to registers
    float xr[64];
    {
        float* xs = smem; // [64][65]
        #pragma unroll
        for (int q = 0; q < 4; ++q) {
            int f4 = t * 4 + q;             // 1024 float4s
            int r = f4 >> 4, c4 = f4 & 15;
            float4 v = *(const float4*)(x + (size_t)(rowbase + r) * 64 + c4 * 4);
            xs[r * 65 + c4 * 4 + 0] = v.x;
            xs[r * 65 + c4 * 4 + 1] = v.y;
            xs[r * 65 + c4 * 4 + 2] = v.z;
            xs[r * 65 + c4 * 4 + 3] = v.w;
        }
        __syncthreads();
        #pragma unroll
        for (int j = 0; j < 64; ++j) xr[j] = xs[lane * 65 + j];
        __syncthreads(); // xs dead, region becomes h1T
    }

    // ---- phase 1: layer1 -> h1T[c][lane]; weights via vmem double-buffer
    {
        float* h1T = smem; // [256][65]
        const float* W1v = W1 + lz;
        const float* b1v = b1 + lz;
        for (int cc = 0; cc < 64; cc += 8) {
            const int c0 = wave * 64 + cc;
            const float* wrow = W1v + c0 * 64;   // 8 consecutive rows of We1 (stride 64)
            float4 wa[8], wb[8];
            #pragma unroll
            for (int u = 0; u < 8; ++u) wa[u] = ldf4(wrow + u * 64);
            float acc[8] = {0.f, 0.f, 0.f, 0.f, 0.f, 0.f, 0.f, 0.f};
            #pragma unroll 1
            for (int jq = 0; jq < 16; jq += 2) {
                const float* r1 = wrow + (jq + 1) * 4;
                #pragma unroll
                for (int u = 0; u < 8; ++u) wb[u] = ldf4(r1 + u * 64);
                #pragma unroll
                for (int u = 0; u < 8; ++u) {
                    acc[u] = __builtin_fmaf(wa[u].x, xr[jq * 4 + 0], acc[u]);
                    acc[u] = __builtin_fmaf(wa[u].y, xr[jq * 4 + 1], acc[u]);
                    acc[u] = __builtin_fmaf(wa[u].z, xr[jq * 4 + 2], acc[u]);
                    acc[u] = __builtin_fmaf(wa[u].w, xr[jq * 4 + 3], acc[u]);
                }
                const int jn = (jq + 2 < 16) ? (jq + 2) * 4 : 0;  // clamp: avoid OOB past We1
                const float* r2 = wrow + jn;
                #pragma unroll
                for (int u = 0; u < 8; ++u) wa[u] = ldf4(r2 + u * 64);
                #pragma unroll
                for (int u = 0; u < 8; ++u) {
                    acc[u] = __builtin_fmaf(wb[u].x, xr[jq * 4 + 4], acc[u]);
                    acc[u] = __builtin_fmaf(wb[u].y, xr[jq * 4 + 5], acc[u]);
                    acc[u] = __builtin_fmaf(wb[u].z, xr[jq * 4 + 6], acc[u]);
                    acc[u] = __builtin_fmaf(wb[u].w, xr[jq * 4 + 7], acc[u]);
                }
            }
            #pragma unroll
            for (int u = 0; u < 8; ++u) {
                int c = c0 + u;
                h1T[c * 65 + lane] = selu_f(acc[u] + b1v[c]);
            }
        }
        __syncthreads();
    }

    // ---- phase 2: layer2, all 64 wave-columns at once; W2T rows double-buffered via vmem
    float acc[64];
    #pragma unroll
    for (int i = 0; i < 64; ++i) acc[i] = 0.0f;
    {
        const float* h1T = smem;
        const int c0 = wave * 64;
        const float* w2b = W2T + lz + c0;          // row j at w2b + j*256, 64 consecutive floats
        float4 wa[16], wb[16];
        #pragma unroll
        for (int q = 0; q < 16; ++q) wa[q] = ldf4(w2b + q * 4);
        #pragma unroll 1
        for (int j = 0; j < 256; j += 2) {
            const float* r1 = w2b + (j + 1) * 256;
            #pragma unroll
            for (int q = 0; q < 16; ++q) wb[q] = ldf4(r1 + q * 4);
            float hv = h1T[j * 65 + lane];
            #pragma unroll
            for (int q = 0; q < 16; ++q) {
                acc[q * 4 + 0] = __builtin_fmaf(wa[q].x, hv, acc[q * 4 + 0]);
                acc[q * 4 + 1] = __builtin_fmaf(wa[q].y, hv, acc[q * 4 + 1]);
                acc[q * 4 + 2] = __builtin_fmaf(wa[q].z, hv, acc[q * 4 + 2]);
                acc[q * 4 + 3] = __builtin_fmaf(wa[q].w, hv, acc[q * 4 + 3]);
            }
            const float* r2 = w2b + (j + 2) * 256; // j=254 -> row 256: lands in W3T region (in-ws, unused)
            #pragma unroll
            for (int q = 0; q < 16; ++q) wa[q] = ldf4(r2 + q * 4);
            float hv2 = h1T[(j + 1) * 65 + lane];
            #pragma unroll
            for (int q = 0; q < 16; ++q) {
                acc[q * 4 + 0] = __builtin_fmaf(wb[q].x, hv2, acc[q * 4 + 0]);
                acc[q * 4 + 1] = __builtin_fmaf(wb[q].y, hv2, acc[q * 4 + 1]);
                acc[q * 4 + 2] = __builtin_fmaf(wb[q].z, hv2, acc[q * 4 + 2]);
                acc[q * 4 + 3] = __builtin_fmaf(wb[q].w, hv2, acc[q * 4 + 3]);
            }
        }
    }

    // ---- phase 2b: fold h2 = selu(acc + b2) into z partials via W3T, two e-halves (VGPR cap)
    float zacc[64];
    #pragma unroll
    for (int e = 0; e < 64; ++e) zacc[e] = 0.0f;
    {
        const int c0 = wave * 64;
        const float* b2v = b2 + lz;
        const float* W3v = W3T + lz;
        #pragma unroll
        for (int h = 0; h < 2; ++h) {
            const float* w3h = W3v + h * 32;       // e-half offset within 64-float rows
            float4 va[8], vb[8];
            #pragma unroll
            for (int q = 0; q < 8; ++q) va[q] = ldf4(w3h + c0 * 64 + q * 4);
            #pragma unroll 1
            for (int u = 0; u < 64; u += 2) {
                const float* r1 = w3h + (c0 + u + 1) * 64;
                #pragma unroll
                for (int q = 0; q < 8; ++q) vb[q] = ldf4(r1 + q * 4);
                float h2v;
                if (h == 0) { h2v = selu_f(acc[u] + b2v[c0 + u]); acc[u] = h2v; }
                else        { h2v = acc[u]; }
                #pragma unroll
                for (int q = 0; q < 8; ++q) {
                    zacc[h * 32 + q * 4 + 0] = __builtin_fmaf(va[q].x, h2v, zacc[h * 32 + q * 4 + 0]);
                    zacc[h * 32 + q * 4 + 1] = __builtin_fmaf(va[q].y, h2v, zacc[h * 32 + q * 4 + 1]);
                    zacc[h * 32 + q * 4 + 2] = __builtin_fmaf(va[q].z, h2v, zacc[h * 32 + q * 4 + 2]);
                    zacc[h * 32 + q * 4 + 3] = __builtin_fmaf(va[q].w, h2v, zacc[h * 32 + q * 4 + 3]);
                }
                const float* r2 = w3h + (c0 + u + 2) * 64; // c0=192,u=62 -> row 256: en region (in-ws, unused)
                #pragma unroll
                for (int q = 0; q < 8; ++q) va[q] = ldf4(r2 + q * 4);
                float h2w;
                if (h == 0) { h2w = selu_f(acc[u + 1] + b2v[c0 + u + 1]); acc[u + 1] = h2w; }
                else        { h2w = acc[u + 1]; }
                #pragma unroll
                for (int q = 0; q < 8; ++q) {
                    zacc[h * 32 + q * 4 + 0] = __builtin_fmaf(vb[q].x, h2w, zacc[h * 32 + q * 4 + 0]);
                    zacc[h * 32 + q * 4 + 1] = __builtin_fmaf(vb[q].y, h2w, zacc[h * 32 + q * 4 + 1]);
                    zacc[h * 32 + q * 4 + 2] = __builtin_fmaf(vb[q].z, h2w, zacc[h * 32 + q * 4 + 2]);
                    zacc[h * 32 + q * 4 + 3] = __builtin_fmaf(vb[q].w, h2w, zacc[h * 32 + q * 4 + 3]);
                }
            }
        }
    }
    __syncthreads(); // all waves done reading h1T

    // ---- phase 3: write z partials, cross-wave reduce, z regs + A = ||z||^2 (numpy pairwise)
    {
        float* zp = smem; // [4*64][65]
        #pragma unroll
        for (int e = 0; e < 64; ++e) zp[(wave * 64 + e) * 65 + lane] = zacc[e];
    }
    __syncthreads();
    float z[64];
    float A;
    {
        const float* zp = smem;
        const float* b3v = b3 + lz;
        #pragma unroll
        for (int e = 0; e < 64; ++e) {
            float s01 = zp[e * 65 + lane] + zp[(64 + e) * 65 + lane];
            float s23 = zp[(128 + e) * 65 + lane] + zp[(192 + e) * 65 + lane];
            z[e] = (s01 + s23) + b3v[e];   // bias added after full dot, matching np
        }
        float r[8];
        #pragma unroll
        for (int u = 0; u < 8; ++u) r[u] = z[u] * z[u];
        #pragma unroll
        for (int i = 8; i < 64; i += 8) {
            #pragma unroll
            for (int u = 0; u < 8; ++u) { float p = z[i + u] * z[i + u]; r[u] = r[u] + p; }
        }
        A = ((r[0] + r[1]) + (r[2] + r[3])) + ((r[4] + r[5]) + (r[6] + r[7]));
    }

    // ---- phase 4: scores over wave's k-slice; emb rows double-buffered via vmem
    float best = 3.4e38f;
    int   bk   = wave * 256;
    {
        const float* embv = emb + lz;
        const float* env  = en + lz;
        const int k0 = wave * 256;
        float4 ea[16], eb[16];
        float enA, enB;
        {
            const float* r0 = embv + (size_t)k0 * 64;
            #pragma unroll
            for (int q = 0; q < 16; ++q) ea[q] = ldf4(r0 + q * 4);
            enA = env[k0];
        }
        #pragma unroll 1
        for (int kk = 0; kk < 256; kk += 2) {
            const float* r1 = embv + (size_t)(k0 + kk + 1) * 64;
            #pragma unroll
            for (int q = 0; q < 16; ++q) eb[q] = ldf4(r1 + q * 4);
            enB = env[k0 + kk + 1];
            {   // score code k0+kk with ea
                float d0 = 0.f, d1 = 0.f, d2 = 0.f, d3 = 0.f;
                #pragma unroll
                for (int q = 0; q < 16; ++q) {
                    d0 = __builtin_fmaf(z[q * 4 + 0], ea[q].x, d0);
                    d1 = __builtin_fmaf(z[q * 4 + 1], ea[q].y, d1);
                    d2 = __builtin_fmaf(z[q * 4 + 2], ea[q].z, d2);
                    d3 = __builtin_fmaf(z[q * 4 + 3], ea[q].w, d3);
                }
                float dot = (d0 + d1) + (d2 + d3);
                float s   = __builtin_fmaf(-2.0f, dot, A) + enA;
                if (s < best) { best = s; bk = k0 + kk; }
            }
            const int kn = (kk + 2 < 256) ? (kk + 2) : 0;  // wrap: dummy reload, never scored
            const float* r2 = embv + (size_t)(k0 + kn) * 64;
            #pragma unroll
            for (int q = 0; q < 16; ++q) ea[q] = ldf4(r2 + q * 4);
            enA = env[k0 + kn];
            {   // score code k0+kk+1 with eb
                float d0 = 0.f, d1 = 0.f, d2 = 0.f, d3 = 0.f;
                #pragma unroll
                for (int q = 0; q < 16; ++q) {
                    d0 = __builtin_fmaf(z[q * 4 + 0], eb[q].x, d0);
                    d1 = __builtin_fmaf(z[q * 4 + 1], eb[q].y, d1);
                    d2 = __builtin_fmaf(z[q * 4 + 2], eb[q].z, d2);
                    d3 = __builtin_fmaf(z[q * 4 + 3], eb[q].w, d3);
                }
                float dot = (d0 + d1) + (d2 + d3);
                float s   = __builtin_fmaf(-2.0f, dot, A) + enB;
                if (s < best) { best = s; bk = k0 + kk + 1; }
            }
        }
    }

    // ---- phase 5: cross-wave argmin combine (ascending wave => first-min), write idx
    cand_s[wave][lane] = best;
    cand_k[wave][lane] = bk;
    __syncthreads();
    if (t < 64) {
        float s0 = cand_s[0][t];
        int   k0i = cand_k[0][t];
        #pragma unroll
        for (int w2 = 1; w2 < 4; ++w2) {
            float sw = cand_s[w2][t];
            if (sw < s0) { s0 = sw; k0i = cand_k[w2][t]; }
        }
        ix[t] = k0i;
        out[(size_t)NROWS * 64 + rowbase + t] = (float)k0i; // idx as float
    }
    __syncthreads();

    // ---- phase 6: recon = dec_out[idx] gather, coalesced store
    #pragma unroll
    for (int q = 0; q < 4; ++q) {
        int f4 = t * 4 + q;
        int r = f4 >> 4, c4 = f4 & 15;
        float4 v = *(const float4*)(dec_out + (size_t)ix[r] * 64 + c4 * 4);
        *(float4*)(out + (size_t)(rowbase + r) * 64 + c4 * 4) = v;
    }
}

extern "C" void kernel_launch(void* const* d_in, const int* in_sizes, int n_in,
                              void* d_out, int out_size, void* d_ws, size_t ws_size,
                              hipStream_t stream) {
    const float* x   = (const float*)d_in[0];
    const float* We1 = (const float*)d_in[1];
    const float* be1 = (const float*)d_in[2];
    const float* We2 = (const float*)d_in[3];
    const float* be2 = (const float*)d_in[4];
    const float* We3 = (const float*)d_in[5];
    const float* be3 = (const float*)d_in[6];
    const float* emb = (const float*)d_in[7];
    const float* Wd1 = (const float*)d_in[8];
    const float* bd1 = (const float*)d_in[9];
    const float* Wd2 = (const float*)d_in[10];
    const float* bd2 = (const float*)d_in[11];
    const float* Wd3 = (const float*)d_in[12];
    const float* bd3 = (const float*)d_in[13];
    float* out = (float*)d_out;

    char* ws = (char*)d_ws;
    float* dec_out = (float*)(ws);            // 1024*64*4   = 256 KB
    float* W2T     = (float*)(ws + 262144);   // 256*256*4   = 256 KB
    float* W3T     = (float*)(ws + 524288);   // 256*64*4    =  64 KB
    float* en      = (float*)(ws + 589824);   // 1024*4      =   4 KB

    prep_transpose<<<320, 256, 0, stream>>>(We2, We3, W2T, W3T);
    prep_decoder<<<256, 256, 0, stream>>>(emb, Wd1, bd1, Wd2, bd2, Wd3, bd3, dec_out, en);
    vqvae_main<<<NROWS / 64, 256, 0, stream>>>(x, We1, be1, be2, be3, W2T, W3T, emb, en,
                                               dec_out, out);
}

// Round 3
// 2501.575 us; speedup vs baseline: 1.0745x; 1.0745x over previous
//
#include <hip/hip_runtime.h>
#include <math.h>

#pragma clang fp contract(off)

#define NROWS 131072

// selu matching np: scale * where(x>0, x, alpha*expm1(x)), each op rounded separately
__device__ __forceinline__ float selu_f(float v) {
    float em  = expm1f(v);
    float neg = 1.6732632423543772f * em;
    float r   = v > 0.0f ? v : neg;
    return 1.0507009873554805f * r;
}

__device__ __forceinline__ float4 ldf4(const float* p) { return *(const float4*)p; }

__device__ __forceinline__ void ld4x4(float4* b, const float* p) {
    b[0] = ldf4(p); b[1] = ldf4(p + 4); b[2] = ldf4(p + 8); b[3] = ldf4(p + 12);
}

__device__ __forceinline__ void fma16a(float* a, const float4* w, float h) {
    a[0]  = __builtin_fmaf(w[0].x, h, a[0]);  a[1]  = __builtin_fmaf(w[0].y, h, a[1]);
    a[2]  = __builtin_fmaf(w[0].z, h, a[2]);  a[3]  = __builtin_fmaf(w[0].w, h, a[3]);
    a[4]  = __builtin_fmaf(w[1].x, h, a[4]);  a[5]  = __builtin_fmaf(w[1].y, h, a[5]);
    a[6]  = __builtin_fmaf(w[1].z, h, a[6]);  a[7]  = __builtin_fmaf(w[1].w, h, a[7]);
    a[8]  = __builtin_fmaf(w[2].x, h, a[8]);  a[9]  = __builtin_fmaf(w[2].y, h, a[9]);
    a[10] = __builtin_fmaf(w[2].z, h, a[10]); a[11] = __builtin_fmaf(w[2].w, h, a[11]);
    a[12] = __builtin_fmaf(w[3].x, h, a[12]); a[13] = __builtin_fmaf(w[3].y, h, a[13]);
    a[14] = __builtin_fmaf(w[3].z, h, a[14]); a[15] = __builtin_fmaf(w[3].w, h, a[15]);
}

// rotate step: issue next row's 4xf4 loads, then consume current buffer, then rotate in
__device__ __forceinline__ void step16(float* acc, float4* wb, const float* nextp, float h) {
    float4 t0 = ldf4(nextp), t1 = ldf4(nextp + 4), t2 = ldf4(nextp + 8), t3 = ldf4(nextp + 12);
    fma16a(acc, wb, h);
    wb[0] = t0; wb[1] = t1; wb[2] = t2; wb[3] = t3;
}

// ---------- prep 1: W2 [256,256] -> W2T [j][c]; W3 [64,256] -> W3T [c][e]; W1 [256,64] -> W1T [j][c]
__global__ void prep_transpose(const float* __restrict__ W1, const float* __restrict__ W2,
                               const float* __restrict__ W3,
                               float* __restrict__ W1T, float* __restrict__ W2T,
                               float* __restrict__ W3T) {
    int id = blockIdx.x * 256 + threadIdx.x;
    if (id < 65536) { int c = id >> 8, j = id & 255; W2T[j * 256 + c] = W2[id]; }
    int id2 = id - 65536;
    if (id2 >= 0 && id2 < 16384) { int e = id2 >> 8, c = id2 & 255; W3T[c * 64 + e] = W3[id2]; }
    int id3 = id - 81920;
    if (id3 >= 0 && id3 < 16384) { int c = id3 >> 6, j = id3 & 63; W1T[j * 256 + c] = W1[id3]; }
}

// ---------- prep 2: decoder table dec_out[k] = decoder(emb[k]), and en[k] = ||emb_k||^2 ----------
__global__ void prep_decoder(const float* __restrict__ emb,
                             const float* __restrict__ Wd1, const float* __restrict__ bd1,
                             const float* __restrict__ Wd2, const float* __restrict__ bd2,
                             const float* __restrict__ Wd3, const float* __restrict__ bd3,
                             float* __restrict__ dec_out, float* __restrict__ en) {
    __shared__ float e[64];
    __shared__ float h1[256];
    __shared__ float h2[256];
    const int t = threadIdx.x; // 256 threads
    for (int kc = 0; kc < 4; ++kc) {
        const int k = blockIdx.x * 4 + kc;
        __syncthreads();
        if (t < 64) e[t] = emb[k * 64 + t];
        __syncthreads();
        {
            float acc = 0.0f;
            const float* w = Wd1 + t * 64;
            #pragma unroll
            for (int j = 0; j < 64; ++j) acc = __builtin_fmaf(w[j], e[j], acc);
            h1[t] = selu_f(acc + bd1[t]);
        }
        __syncthreads();
        {
            float acc = 0.0f;
            const float* w = Wd2 + t * 256;
            #pragma unroll 8
            for (int j = 0; j < 256; ++j) acc = __builtin_fmaf(w[j], h1[j], acc);
            h2[t] = selu_f(acc + bd2[t]);
        }
        __syncthreads();
        if (t < 64) {
            float acc = 0.0f;
            const float* w = Wd3 + t * 256;
            #pragma unroll 8
            for (int j = 0; j < 256; ++j) acc = __builtin_fmaf(w[j], h2[j], acc);
            dec_out[k * 64 + t] = acc + bd3[t];
        }
        if (t == 0) {
            float r[8];
            #pragma unroll
            for (int u = 0; u < 8; ++u) r[u] = e[u] * e[u];
            #pragma unroll
            for (int i = 8; i < 64; i += 8) {
                #pragma unroll
                for (int u = 0; u < 8; ++u) { float p = e[i + u] * e[i + u]; r[u] = r[u] + p; }
            }
            en[k] = ((r[0] + r[1]) + (r[2] + r[3])) + ((r[4] + r[5]) + (r[6] + r[7]));
        }
    }
}

// ---------- main kernel ----------
// block = 256 threads = 4 waves, 64 rows (lane = row).
// LDS: R1[16384] = h1 (j-pair layout) -> zs (z transposed, stride 68); aux[4096] = xT -> h2 staging -> cand/ix.
// Weights stream from L2 via VMEM (lz-laundered) with a depth-4 register rotate.
__global__ __launch_bounds__(256) __attribute__((amdgpu_waves_per_eu(2)))
void vqvae_main(const float* __restrict__ x,
                const float* __restrict__ b1, const float* __restrict__ b2,
                const float* __restrict__ b3,
                const float* __restrict__ W1T, const float* __restrict__ W2T,
                const float* __restrict__ W3T,
                const float* __restrict__ emb, const float* __restrict__ en,
                const float* __restrict__ dec_out, float* __restrict__ out) {
    __shared__ __align__(16) float R1[16384];
    __shared__ __align__(16) float aux[4096];

    const int t    = threadIdx.x;
    const int wave = t >> 6;
    const int lane = t & 63;
    const size_t rowbase = (size_t)blockIdx.x * 64;

    // opaque zero in a VGPR: keeps uniform loads on the vector pipe (vmcnt, pipelinable)
    int lz;
    asm volatile("v_mov_b32 %0, 0" : "=v"(lz));

    const float* W1Tv = W1T + lz;
    const float* W2Tv = W2T + lz;
    const float* W3Tv = W3T + lz;
    const float* b1v  = b1 + lz;
    const float* b2v  = b2 + lz;
    const float* b3v  = b3 + lz;
    const float* env  = en + lz;
    const float* embv = emb + lz;

    // ---- phase 0: stage x tile transposed into aux: xT[j][r]
    #pragma unroll
    for (int q = 0; q < 4; ++q) {
        int f = t + 256 * q;
        int r = f >> 4, c4 = f & 15;
        float4 v = ldf4(x + (rowbase + r) * 64 + c4 * 4);
        aux[(c4 * 4 + 0) * 64 + r] = v.x;
        aux[(c4 * 4 + 1) * 64 + r] = v.y;
        aux[(c4 * 4 + 2) * 64 + r] = v.z;
        aux[(c4 * 4 + 3) * 64 + r] = v.w;
    }
    __syncthreads();

    // ---- phase 1: layer1. group g: this wave computes cols cg=64g+16*wave .. +16.
    // h1 stored as j-pairs: R1[(c>>1)*128 + lane*2 + (c&1)]
    for (int g = 0; g < 4; ++g) {
        const int cg = g * 64 + wave * 16;
        const float* wp = W1Tv + cg;      // row j at wp + j*256
        float4 A0[4], A1[4], A2[4], A3[4];
        ld4x4(A0, wp); ld4x4(A1, wp + 256); ld4x4(A2, wp + 512); ld4x4(A3, wp + 768);
        float acc[16];
        #pragma unroll
        for (int u = 0; u < 16; ++u) acc[u] = 0.0f;
        #pragma unroll 1
        for (int j = 0; j < 64; j += 4) {
            const float* np = wp + (j + 4) * 256;   // rows 64..67 overrun into W3T region (in-ws, unused)
            step16(acc, A0, np,        aux[(j + 0) * 64 + lane]);
            step16(acc, A1, np + 256,  aux[(j + 1) * 64 + lane]);
            step16(acc, A2, np + 512,  aux[(j + 2) * 64 + lane]);
            step16(acc, A3, np + 768,  aux[(j + 3) * 64 + lane]);
        }
        float bb[16];
        *(float4*)&bb[0]  = ldf4(b1v + cg);
        *(float4*)&bb[4]  = ldf4(b1v + cg + 4);
        *(float4*)&bb[8]  = ldf4(b1v + cg + 8);
        *(float4*)&bb[12] = ldf4(b1v + cg + 12);
        float hv[16];
        #pragma unroll
        for (int u = 0; u < 16; ++u) hv[u] = selu_f(acc[u] + bb[u]);
        #pragma unroll
        for (int up = 0; up < 8; ++up) {
            *(float2*)&R1[((cg >> 1) + up) * 128 + (lane << 1)] = make_float2(hv[2 * up], hv[2 * up + 1]);
        }
    }
    __syncthreads();

    // ---- phase 2: layer2 + layer3, group-staged.
    // group g = col-block [64g, 64g+64): wave computes 16 cols (cg=64g+16*wave), stages h2 in aux,
    // then folds the whole 64-col block into its e-range er=[16*wave, +16) -> partial P_g.
    // z = ((P0+P1)+(P2+P3)) + b3  (identical chain to the passing rounds)
    const int er = wave * 16;
    float s01[16], s23[16];
    for (int g = 0; g < 4; ++g) {
        const int cg = g * 64 + wave * 16;
        const float* wp = W2Tv + cg;      // row j at wp + j*256
        float4 A0[4], A1[4], A2[4], A3[4];
        ld4x4(A0, wp); ld4x4(A1, wp + 256); ld4x4(A2, wp + 512); ld4x4(A3, wp + 768);
        float acc[16];
        #pragma unroll
        for (int u = 0; u < 16; ++u) acc[u] = 0.0f;
        #pragma unroll 1
        for (int j = 0; j < 256; j += 4) {
            const float* np = wp + (j + 4) * 256; // rows 256..259 land in W1T region (in-ws, unused)
            float2 h01 = *(const float2*)&R1[(j >> 1) * 128 + (lane << 1)];
            step16(acc, A0, np,        h01.x);
            step16(acc, A1, np + 256,  h01.y);
            float2 h23 = *(const float2*)&R1[((j >> 1) + 1) * 128 + (lane << 1)];
            step16(acc, A2, np + 512,  h23.x);
            step16(acc, A3, np + 768,  h23.y);
        }
        __syncthreads();   // previous fold's readers of aux are done
        {
            float bb[16];
            *(float4*)&bb[0]  = ldf4(b2v + cg);
            *(float4*)&bb[4]  = ldf4(b2v + cg + 4);
            *(float4*)&bb[8]  = ldf4(b2v + cg + 8);
            *(float4*)&bb[12] = ldf4(b2v + cg + 12);
            #pragma unroll
            for (int u = 0; u < 16; ++u)
                aux[(wave * 16 + u) * 64 + lane] = selu_f(acc[u] + bb[u]);
        }
        __syncthreads();   // h2 of this col-block visible
        // fold col-block g (cols 64g..64g+63 ascending) into e-range er..er+16
        const float* w3p = W3Tv + g * 4096 + er;    // col (64g+c) at w3p + c*64
        float4 F0[4], F1[4], F2[4], F3[4];
        ld4x4(F0, w3p); ld4x4(F1, w3p + 64); ld4x4(F2, w3p + 128); ld4x4(F3, w3p + 192);
        float P[16];
        #pragma unroll
        for (int u = 0; u < 16; ++u) P[u] = 0.0f;
        #pragma unroll 1
        for (int c = 0; c < 64; c += 4) {
            const float* np = w3p + (c + 4) * 64;  // col 256..259 overrun into en pad (in-ws)
            step16(P, F0, np,        aux[(c + 0) * 64 + lane]);
            step16(P, F1, np + 64,   aux[(c + 1) * 64 + lane]);
            step16(P, F2, np + 128,  aux[(c + 2) * 64 + lane]);
            step16(P, F3, np + 192,  aux[(c + 3) * 64 + lane]);
        }
        if (g == 0) {
            #pragma unroll
            for (int u = 0; u < 16; ++u) s01[u] = P[u];
        } else if (g == 1) {
            #pragma unroll
            for (int u = 0; u < 16; ++u) s01[u] = s01[u] + P[u];
        } else if (g == 2) {
            #pragma unroll
            for (int u = 0; u < 16; ++u) s23[u] = P[u];
        } else {
            #pragma unroll
            for (int u = 0; u < 16; ++u) s23[u] = s23[u] + P[u];
        }
    }

    // ---- phase 3: z = (s01+s23)+b3; park z in LDS (zs[lane][e], stride 68 -> 2-way free b128)
    {
        float bb[16];
        *(float4*)&bb[0]  = ldf4(b3v + er);
        *(float4*)&bb[4]  = ldf4(b3v + er + 4);
        *(float4*)&bb[8]  = ldf4(b3v + er + 8);
        *(float4*)&bb[12] = ldf4(b3v + er + 12);
        float zv[16];
        #pragma unroll
        for (int u = 0; u < 16; ++u) zv[u] = (s01[u] + s23[u]) + bb[u];
        #pragma unroll
        for (int m = 0; m < 4; ++m)
            *(float4*)&R1[lane * 68 + er + m * 4] =
                make_float4(zv[4 * m], zv[4 * m + 1], zv[4 * m + 2], zv[4 * m + 3]);
    }
    __syncthreads();

    // A = ||z||^2 with numpy pairwise chain (8 strided accumulators, balanced tree)
    float A;
    {
        float z[64];
        #pragma unroll
        for (int m = 0; m < 16; ++m) {
            float4 v = *(const float4*)&R1[lane * 68 + m * 4];
            z[4 * m] = v.x; z[4 * m + 1] = v.y; z[4 * m + 2] = v.z; z[4 * m + 3] = v.w;
        }
        float r[8];
        #pragma unroll
        for (int u = 0; u < 8; ++u) r[u] = z[u] * z[u];
        #pragma unroll
        for (int i = 8; i < 64; i += 8) {
            #pragma unroll
            for (int u = 0; u < 8; ++u) { float p = z[i + u] * z[i + u]; r[u] = r[u] + p; }
        }
        A = ((r[0] + r[1]) + (r[2] + r[3])) + ((r[4] + r[5]) + (r[6] + r[7]));
    }

    // ---- phase 4: scores over wave's 256-code slice, 8-code chunks, z quarters re-read from LDS
    float best = 3.4e38f;
    const int k0 = wave * 256;
    int bk = k0;
    const float* embw = embv + (size_t)k0 * 64;
    #pragma unroll 1
    for (int kc = 0; kc < 256; kc += 8) {
        float4 en03 = ldf4(env + k0 + kc);
        float4 en47 = ldf4(env + k0 + kc + 4);
        float d0[8], d1[8], d2[8], d3[8];
        #pragma unroll
        for (int c = 0; c < 8; ++c) { d0[c] = 0.f; d1[c] = 0.f; d2[c] = 0.f; d3[c] = 0.f; }
        #pragma unroll
        for (int q = 0; q < 4; ++q) {
            float4 zq0 = *(const float4*)&R1[lane * 68 + q * 16];
            float4 zq1 = *(const float4*)&R1[lane * 68 + q * 16 + 4];
            float4 zq2 = *(const float4*)&R1[lane * 68 + q * 16 + 8];
            float4 zq3 = *(const float4*)&R1[lane * 68 + q * 16 + 12];
            #pragma unroll
            for (int c = 0; c < 8; ++c) {
                const float* ep = embw + (kc + c) * 64 + q * 16;
                float4 e0 = ldf4(ep), e1 = ldf4(ep + 4), e2 = ldf4(ep + 8), e3 = ldf4(ep + 12);
                d0[c] = __builtin_fmaf(zq0.x, e0.x, d0[c]);
                d1[c] = __builtin_fmaf(zq0.y, e0.y, d1[c]);
                d2[c] = __builtin_fmaf(zq0.z, e0.z, d2[c]);
                d3[c] = __builtin_fmaf(zq0.w, e0.w, d3[c]);
                d0[c] = __builtin_fmaf(zq1.x, e1.x, d0[c]);
                d1[c] = __builtin_fmaf(zq1.y, e1.y, d1[c]);
                d2[c] = __builtin_fmaf(zq1.z, e1.z, d2[c]);
                d3[c] = __builtin_fmaf(zq1.w, e1.w, d3[c]);
                d0[c] = __builtin_fmaf(zq2.x, e2.x, d0[c]);
                d1[c] = __builtin_fmaf(zq2.y, e2.y, d1[c]);
                d2[c] = __builtin_fmaf(zq2.z, e2.z, d2[c]);
                d3[c] = __builtin_fmaf(zq2.w, e2.w, d3[c]);
                d0[c] = __builtin_fmaf(zq3.x, e3.x, d0[c]);
                d1[c] = __builtin_fmaf(zq3.y, e3.y, d1[c]);
                d2[c] = __builtin_fmaf(zq3.z, e3.z, d2[c]);
                d3[c] = __builtin_fmaf(zq3.w, e3.w, d3[c]);
            }
        }
        float enb[8];
        *(float4*)&enb[0] = en03; *(float4*)&enb[4] = en47;
        #pragma unroll
        for (int c = 0; c < 8; ++c) {
            float dot = (d0[c] + d1[c]) + (d2[c] + d3[c]);
            float tt  = __builtin_fmaf(-2.0f, dot, A);
            float s   = tt + enb[c];
            if (s < best) { best = s; bk = k0 + kc + c; }
        }
    }

    // ---- phase 5: cross-wave argmin (ascending wave => first-min); aux now dead -> cand storage
    float* cand_s = aux + 64;
    int*   cand_k = ((int*)aux) + 320;
    int*   ixp    = (int*)aux;
    cand_s[wave * 64 + lane] = best;
    cand_k[wave * 64 + lane] = bk;
    __syncthreads();
    if (t < 64) {
        float s0 = cand_s[t];
        int   kk = cand_k[t];
        #pragma unroll
        for (int w2 = 1; w2 < 4; ++w2) {
            float sw = cand_s[w2 * 64 + t];
            if (sw < s0) { s0 = sw; kk = cand_k[w2 * 64 + t]; }
        }
        ixp[t] = kk;
        out[(size_t)NROWS * 64 + rowbase + t] = (float)kk;
    }
    __syncthreads();

    // ---- phase 6: recon = dec_out[idx], coalesced f4 store
    #pragma unroll
    for (int q = 0; q < 4; ++q) {
        int f = t + 256 * q;
        int r = f >> 4, c4 = f & 15;
        float4 v = ldf4(dec_out + (size_t)ixp[r] * 64 + c4 * 4);
        *(float4*)(out + (rowbase + r) * 64 + c4 * 4) = v;
    }
}

extern "C" void kernel_launch(void* const* d_in, const int* in_sizes, int n_in,
                              void* d_out, int out_size, void* d_ws, size_t ws_size,
                              hipStream_t stream) {
    const float* x   = (const float*)d_in[0];
    const float* We1 = (const float*)d_in[1];
    const float* be1 = (const float*)d_in[2];
    const float* We2 = (const float*)d_in[3];
    const float* be2 = (const float*)d_in[4];
    const float* We3 = (const float*)d_in[5];
    const float* be3 = (const float*)d_in[6];
    const float* emb = (const float*)d_in[7];
    const float* Wd1 = (const float*)d_in[8];
    const float* bd1 = (const float*)d_in[9];
    const float* Wd2 = (const float*)d_in[10];
    const float* bd2 = (const float*)d_in[11];
    const float* Wd3 = (const float*)d_in[12];
    const float* bd3 = (const float*)d_in[13];
    float* out = (float*)d_out;

    // ws layout (floats): dec_out[65536] | W2T[65536] | W1T[16384] | W3T[16384] | en[1024+pad]
    float* ws      = (float*)d_ws;
    float* dec_out = ws;
    float* W2T     = ws + 65536;
    float* W1T     = ws + 131072;
    float* W3T     = ws + 147456;
    float* en      = ws + 163840;   // en + 1 KB pad absorbs fold prefetch overrun

    prep_transpose<<<384, 256, 0, stream>>>(We1, We2, We3, W1T, W2T, W3T);
    prep_decoder<<<256, 256, 0, stream>>>(emb, Wd1, bd1, Wd2, bd2, Wd3, bd3, dec_out, en);
    vqvae_main<<<NROWS / 64, 256, 0, stream>>>(x, be1, be2, be3, W1T, W2T, W3T, emb, en,
                                               dec_out, out);
}